// Round 3
// baseline (124664.136 us; speedup 1.0000x reference)
//
#include <hip/hip_runtime.h>
#include <hip/hip_bf16.h>

// Problem dims
constexpr int kH  = 2048;          // hidden
constexpr int kD  = 1024;          // input dim
constexpr int kT  = 4096;          // timesteps
constexpr int kTH = 3 * kH;        // 6144 gate rows
constexpr int kNB = 256;           // GRU grid blocks (both sequences)

// ---------------------------------------------------------------------------
// Workspace layout:
//   xp1   : kT*kTH fp32
//   xp2   : kT*kTH fp32
//   hbufs : 4 * kH fp32
//   sync  : 1024 u32 (grid barrier counters; re-poisoned -> init kernel zeroes)
// Round-2 post-mortem: rounds 1 & 2 gave bit-identical absmax 5.47e-2 ==
// head(h=0) vs ref -> hipLaunchCooperativeKernel silently failed both times.
// This version uses a NORMAL launch + manual device-scope grid barrier.
// Co-residency: 384-VGPR weight array forces 1 block/CU; grid == 256 == #CUs.
// ---------------------------------------------------------------------------

__global__ void init_sync_kernel(unsigned* __restrict__ sync) {
    sync[threadIdx.x] = 0u;   // 1024 words, one block of 1024 threads
}

// fp32 tiled GEMM: xp[t][j] = sum_k x[t][k] * Wih[j][k] + bih[j]
__global__ __launch_bounds__(256) void gemm_xp_kernel(
    const float* __restrict__ x1, const float* __restrict__ x2,
    const float* __restrict__ Wih1, const float* __restrict__ Wih2,
    const float* __restrict__ bih1, const float* __restrict__ bih2,
    float* __restrict__ xp1, float* __restrict__ xp2) {
    const float* x  = blockIdx.z ? x2   : x1;
    const float* W  = blockIdx.z ? Wih2 : Wih1;
    const float* bi = blockIdx.z ? bih2 : bih1;
    float*       xp = blockIdx.z ? xp2  : xp1;

    __shared__ float As[16][68];
    __shared__ float Bs[16][68];

    const int tid  = threadIdx.x;
    const int tx   = tid & 15, ty = tid >> 4;
    const int lrow = tid >> 2;
    const int lk   = (tid & 3) * 4;
    const int m0   = blockIdx.y * 64;
    const int n0   = blockIdx.x * 64;

    float acc[4][4] = {};

    for (int k0 = 0; k0 < kD; k0 += 16) {
        float4 av = *(const float4*)(x + (size_t)(m0 + lrow) * kD + k0 + lk);
        float4 bv = *(const float4*)(W + (size_t)(n0 + lrow) * kD + k0 + lk);
        __syncthreads();
        As[lk + 0][lrow] = av.x; As[lk + 1][lrow] = av.y;
        As[lk + 2][lrow] = av.z; As[lk + 3][lrow] = av.w;
        Bs[lk + 0][lrow] = bv.x; Bs[lk + 1][lrow] = bv.y;
        Bs[lk + 2][lrow] = bv.z; Bs[lk + 3][lrow] = bv.w;
        __syncthreads();
#pragma unroll
        for (int kk = 0; kk < 16; ++kk) {
            float4 a = *(const float4*)&As[kk][ty * 4];
            float4 b = *(const float4*)&Bs[kk][tx * 4];
            float aa[4] = {a.x, a.y, a.z, a.w};
            float bb[4] = {b.x, b.y, b.z, b.w};
#pragma unroll
            for (int i = 0; i < 4; ++i)
#pragma unroll
                for (int j = 0; j < 4; ++j)
                    acc[i][j] = fmaf(aa[i], bb[j], acc[i][j]);
        }
    }

    float4 bb4 = *(const float4*)(bi + n0 + tx * 4);
    float bArr[4] = {bb4.x, bb4.y, bb4.z, bb4.w};
#pragma unroll
    for (int i = 0; i < 4; ++i) {
        float4 o;
        o.x = acc[i][0] + bArr[0];
        o.y = acc[i][1] + bArr[1];
        o.z = acc[i][2] + bArr[2];
        o.w = acc[i][3] + bArr[3];
        *(float4*)(xp + (size_t)(m0 + ty * 4 + i) * kTH + n0 + tx * 4) = o;
    }
}

// Two-level grid barrier, device scope. sync layout (64-word = 256 B strides):
//   sync[g*64]   g=0..7 : group arrival counters (32 blocks each)
//   sync[8*64]          : master counter (8 groups)
//   sync[9*64]          : generation
__device__ __forceinline__ void grid_barrier(unsigned* __restrict__ sync,
                                             unsigned target) {
    __syncthreads();
    if (threadIdx.x == 0) {
        __threadfence();                       // release this block's stores
        unsigned* gcnt = sync + (blockIdx.x >> 5) * 64;
        unsigned* mcnt = sync + 8 * 64;
        unsigned* gen  = sync + 9 * 64;
        bool released = false;
        unsigned p = __hip_atomic_fetch_add(gcnt, 1u, __ATOMIC_ACQ_REL,
                                            __HIP_MEMORY_SCOPE_AGENT);
        if (p == 31u) {
            __hip_atomic_store(gcnt, 0u, __ATOMIC_RELAXED,
                               __HIP_MEMORY_SCOPE_AGENT);
            unsigned q = __hip_atomic_fetch_add(mcnt, 1u, __ATOMIC_ACQ_REL,
                                                __HIP_MEMORY_SCOPE_AGENT);
            if (q == 7u) {
                __hip_atomic_store(mcnt, 0u, __ATOMIC_RELAXED,
                                   __HIP_MEMORY_SCOPE_AGENT);
                __hip_atomic_fetch_add(gen, 1u, __ATOMIC_RELEASE,
                                       __HIP_MEMORY_SCOPE_AGENT);
                released = true;
            }
        }
        if (!released) {
            while (__hip_atomic_load(gen, __ATOMIC_ACQUIRE,
                                     __HIP_MEMORY_SCOPE_AGENT) < target) {
                __builtin_amdgcn_s_sleep(2);
            }
        }
        __threadfence();                       // acquire remote stores
    }
    __syncthreads();
}

// Persistent GRU, BOTH sequences, normal launch + manual barrier.
// 256 blocks x 256 threads, 1 block/CU. Block b: sequence s=b>>7, indices
// [i0,i0+16). Each wave holds 12 of the block's 48 fp32 W_hh rows in regs
// (w[12][32] = 384 VGPR; lane l holds cols [32l,32l+32)).
__global__ __launch_bounds__(256, 1) void gru_pair_kernel(
    const float* __restrict__ xp1, const float* __restrict__ xp2,
    const float* __restrict__ Whh1, const float* __restrict__ Whh2,
    const float* __restrict__ bhh1, const float* __restrict__ bhh2,
    float* __restrict__ h1b0, float* __restrict__ h1b1,
    float* __restrict__ h2b0, float* __restrict__ h2b1,
    unsigned* __restrict__ sync) {
    const int tid  = threadIdx.x;
    const int lane = tid & 63;
    const int wv   = tid >> 6;
    const int b    = blockIdx.x;
    const int s    = b >> 7;
    const int i0   = (b & 127) * 16;
    const float* xp  = s ? xp2  : xp1;
    const float* Whh = s ? Whh2 : Whh1;
    const float* bhh = s ? bhh2 : bhh1;
    float* hb0 = s ? h2b0 : h1b0;
    float* hb1 = s ? h2b1 : h1b1;

    __shared__ float h_s[kH];
    __shared__ float hp_s[48];

    // one-time register-resident weight load: lr = wv*12+p, gate g=lr>>4,
    // idx j=lr&15, global row rg = g*kH + i0 + j
    float w[12][32];
    float bias[12];
#pragma unroll
    for (int p = 0; p < 12; ++p) {
        const int lr = wv * 12 + p;
        const int g  = lr >> 4, j = lr & 15;
        const int rg = g * kH + i0 + j;
        bias[p] = bhh[rg];
        const float* wr = Whh + (size_t)rg * kH + lane * 32;
#pragma unroll
        for (int e = 0; e < 8; ++e) {
            float4 v = ((const float4*)wr)[e];
            w[p][e * 4 + 0] = v.x; w[p][e * 4 + 1] = v.y;
            w[p][e * 4 + 2] = v.z; w[p][e * 4 + 3] = v.w;
        }
    }
    for (int k = tid; k < kH; k += 256) h_s[k] = 0.f;
    __syncthreads();

    float xr = 0.f, xz = 0.f, xn = 0.f;
    if (tid < 16) {
        const int i = i0 + tid;
        xr = xp[i]; xz = xp[kH + i]; xn = xp[2 * kH + i];
    }

    for (int t = 0; t < kT; ++t) {
        // matvec: 12 rows/wave, weights in regs, h from LDS
        float acc[12];
#pragma unroll
        for (int p = 0; p < 12; ++p) acc[p] = 0.f;
#pragma unroll
        for (int e = 0; e < 8; ++e) {
            const float4 hv = *(const float4*)&h_s[lane * 32 + e * 4];
#pragma unroll
            for (int p = 0; p < 12; ++p) {
                acc[p] = fmaf(w[p][e * 4 + 0], hv.x, acc[p]);
                acc[p] = fmaf(w[p][e * 4 + 1], hv.y, acc[p]);
                acc[p] = fmaf(w[p][e * 4 + 2], hv.z, acc[p]);
                acc[p] = fmaf(w[p][e * 4 + 3], hv.w, acc[p]);
            }
        }
#pragma unroll
        for (int p = 0; p < 12; ++p) {
            float a = acc[p];
#pragma unroll
            for (int off = 32; off; off >>= 1) a += __shfl_down(a, off, 64);
            if (lane == 0) hp_s[wv * 12 + p] = a + bias[p];
        }
        __syncthreads();

        // gates + h update (threads 0..15 own the block's 16 indices)
        float* dst = ((t + 1) & 1) ? hb1 : hb0;
        if (tid < 16) {
            const int i = i0 + tid;
            const float r = 1.f / (1.f + expf(-(xr + hp_s[tid])));
            const float z = 1.f / (1.f + expf(-(xz + hp_s[16 + tid])));
            const float n = tanhf(xn + r * hp_s[32 + tid]);
            dst[i] = (1.f - z) * n + z * h_s[i];
        }

        grid_barrier(sync, (unsigned)(t + 1));

        // prefetch xp for t+1
        if (t + 1 < kT && tid < 16) {
            const int i = i0 + tid;
            const float* xpt = xp + (size_t)(t + 1) * kTH;
            xr = xpt[i]; xz = xpt[kH + i]; xn = xpt[2 * kH + i];
        }
        // reload full h into LDS
        for (int k = tid; k < kH; k += 256) h_s[k] = dst[k];
        __syncthreads();
    }
}

// fc1(relu) -> fc2 -> log_softmax, single block of 256 threads
__global__ __launch_bounds__(256) void head_kernel(
    const float* __restrict__ h1, const float* __restrict__ h2,
    const float* __restrict__ fc1w, const float* __restrict__ fc1b,
    const float* __restrict__ fc2w, const float* __restrict__ fc2b,
    float* __restrict__ out) {
    __shared__ float cat[2 * kH];
    __shared__ float o1[256];
    __shared__ float logits[3];
    const int tid  = threadIdx.x;
    const int lane = tid & 63;
    const int wave = tid >> 6;

    for (int k = tid; k < kH; k += 256) {
        cat[k]      = h1[k];
        cat[kH + k] = h2[k];
    }
    __syncthreads();

    for (int r = wave; r < 256; r += 4) {
        const float* wr = fc1w + (size_t)r * (2 * kH);
        float acc = 0.f;
        for (int j = lane; j < 2 * kH; j += 64) acc = fmaf(wr[j], cat[j], acc);
#pragma unroll
        for (int off = 32; off; off >>= 1) acc += __shfl_down(acc, off, 64);
        if (lane == 0) o1[r] = fmaxf(acc + fc1b[r], 0.f);
    }
    __syncthreads();

    if (tid < 3) {
        float acc = fc2b[tid];
        const float* wr = fc2w + tid * 256;
        for (int j = 0; j < 256; ++j) acc = fmaf(wr[j], o1[j], acc);
        logits[tid] = acc;
    }
    __syncthreads();

    if (tid == 0) {
        float m = fmaxf(logits[0], fmaxf(logits[1], logits[2]));
        float s = expf(logits[0] - m) + expf(logits[1] - m) + expf(logits[2] - m);
        float ls = logf(s);
        out[0] = logits[0] - m - ls;
        out[1] = logits[1] - m - ls;
        out[2] = logits[2] - m - ls;
    }
}

extern "C" void kernel_launch(void* const* d_in, const int* in_sizes, int n_in,
                              void* d_out, int out_size, void* d_ws,
                              size_t ws_size, hipStream_t stream) {
    const float* x1   = (const float*)d_in[0];
    const float* x2   = (const float*)d_in[1];
    const float* Wih1 = (const float*)d_in[2];
    const float* Whh1 = (const float*)d_in[3];
    const float* bih1 = (const float*)d_in[4];
    const float* bhh1 = (const float*)d_in[5];
    const float* Wih2 = (const float*)d_in[6];
    const float* Whh2 = (const float*)d_in[7];
    const float* bih2 = (const float*)d_in[8];
    const float* bhh2 = (const float*)d_in[9];
    const float* fc1w = (const float*)d_in[10];
    const float* fc1b = (const float*)d_in[11];
    const float* fc2w = (const float*)d_in[12];
    const float* fc2b = (const float*)d_in[13];
    float* out = (float*)d_out;

    char* ws = (char*)d_ws;
    float* xp1 = (float*)ws;
    float* xp2 = xp1 + (size_t)kT * kTH;
    float* hb  = xp2 + (size_t)kT * kTH;
    float* h1b0 = hb;
    float* h1b1 = hb + kH;
    float* h2b0 = hb + 2 * kH;
    float* h2b1 = hb + 3 * kH;
    unsigned* sync = (unsigned*)(hb + 4 * kH);

    init_sync_kernel<<<1, 1024, 0, stream>>>(sync);

    gemm_xp_kernel<<<dim3(kTH / 64, kT / 64, 2), 256, 0, stream>>>(
        x1, x2, Wih1, Wih2, bih1, bih2, xp1, xp2);

    gru_pair_kernel<<<dim3(kNB), dim3(256), 0, stream>>>(
        xp1, xp2, Whh1, Whh2, bhh1, bhh2, h1b0, h1b1, h2b0, h2b1, sync);

    head_kernel<<<1, 256, 0, stream>>>(h1b0, h2b0, fc1w, fc1b, fc2w, fc2b, out);
}

// Round 5
// 43377.560 us; speedup vs baseline: 2.8739x; 2.8739x over previous
//
#include <hip/hip_runtime.h>
#include <hip/hip_bf16.h>

// Problem dims
constexpr int kH  = 2048;          // hidden
constexpr int kD  = 1024;          // input dim
constexpr int kT  = 4096;          // timesteps
constexpr int kTH = 3 * kH;        // 6144 gate rows
constexpr int kNB = 256;           // GRU grid blocks (both sequences)

// ---------------------------------------------------------------------------
// Round-3 post-mortem (121.8 ms GRU, 29.7 us/step):
//  * VGPR_Count=228: 384-float weight array exceeded the 256 addressable
//    arch VGPRs -> compiler moved it to AGPRs. Fix: 512 thr/block ->
//    192 floats/thread.
//  * ~28 us/step was barrier cache-maintenance: ACQ_REL arrivals + ACQUIRE
//    spin polls each emit buffer_inv/buffer_wbl2 at agent scope -> L2
//    inv/wb storm from 256 CUs. Fix: RELEASE arrivals, RELAXED polls, one
//    ACQUIRE fence per block per step.
//  * SQ_LDS_BANK_CONFLICT 9.4e8: h_s[lane*32] stride -> all lanes on same
//    banks. Fix: lane-contiguous layout h_s[e*256 + lane*4].
// Round-4: __hip_atomic_thread_fence doesn't exist -> use
// __builtin_amdgcn_fence(order, "agent").
// ---------------------------------------------------------------------------

__global__ void init_sync_kernel(unsigned* __restrict__ sync) {
    sync[threadIdx.x] = 0u;   // 1024 words
}

// fp32 tiled GEMM: xp[t][j] = sum_k x[t][k] * Wih[j][k] + bih[j]
__global__ __launch_bounds__(256) void gemm_xp_kernel(
    const float* __restrict__ x1, const float* __restrict__ x2,
    const float* __restrict__ Wih1, const float* __restrict__ Wih2,
    const float* __restrict__ bih1, const float* __restrict__ bih2,
    float* __restrict__ xp1, float* __restrict__ xp2) {
    const float* x  = blockIdx.z ? x2   : x1;
    const float* W  = blockIdx.z ? Wih2 : Wih1;
    const float* bi = blockIdx.z ? bih2 : bih1;
    float*       xp = blockIdx.z ? xp2  : xp1;

    __shared__ float As[16][68];
    __shared__ float Bs[16][68];

    const int tid  = threadIdx.x;
    const int tx   = tid & 15, ty = tid >> 4;
    const int lrow = tid >> 2;
    const int lk   = (tid & 3) * 4;
    const int m0   = blockIdx.y * 64;
    const int n0   = blockIdx.x * 64;

    float acc[4][4] = {};

    for (int k0 = 0; k0 < kD; k0 += 16) {
        float4 av = *(const float4*)(x + (size_t)(m0 + lrow) * kD + k0 + lk);
        float4 bv = *(const float4*)(W + (size_t)(n0 + lrow) * kD + k0 + lk);
        __syncthreads();
        As[lk + 0][lrow] = av.x; As[lk + 1][lrow] = av.y;
        As[lk + 2][lrow] = av.z; As[lk + 3][lrow] = av.w;
        Bs[lk + 0][lrow] = bv.x; Bs[lk + 1][lrow] = bv.y;
        Bs[lk + 2][lrow] = bv.z; Bs[lk + 3][lrow] = bv.w;
        __syncthreads();
#pragma unroll
        for (int kk = 0; kk < 16; ++kk) {
            float4 a = *(const float4*)&As[kk][ty * 4];
            float4 b = *(const float4*)&Bs[kk][tx * 4];
            float aa[4] = {a.x, a.y, a.z, a.w};
            float bb[4] = {b.x, b.y, b.z, b.w};
#pragma unroll
            for (int i = 0; i < 4; ++i)
#pragma unroll
                for (int j = 0; j < 4; ++j)
                    acc[i][j] = fmaf(aa[i], bb[j], acc[i][j]);
        }
    }

    float4 bb4 = *(const float4*)(bi + n0 + tx * 4);
    float bArr[4] = {bb4.x, bb4.y, bb4.z, bb4.w};
#pragma unroll
    for (int i = 0; i < 4; ++i) {
        float4 o;
        o.x = acc[i][0] + bArr[0];
        o.y = acc[i][1] + bArr[1];
        o.z = acc[i][2] + bArr[2];
        o.w = acc[i][3] + bArr[3];
        *(float4*)(xp + (size_t)(m0 + ty * 4 + i) * kTH + n0 + tx * 4) = o;
    }
}

// Two-level grid barrier. sync layout (64-word = 256 B strides):
//   sync[g*64] g=0..7 : group arrival counters (32 blocks each)
//   sync[512]         : master counter (8 groups)
//   sync[576]         : generation (monotonic)
// Cache-maintenance budget per block per step: one wbl2 (arrival release) +
// one inv (post-pass acquire fence). Spin polls are RELAXED -> no cache ops.
__device__ __forceinline__ void grid_barrier(unsigned* __restrict__ sync,
                                             unsigned target) {
    __syncthreads();
    if (threadIdx.x == 0) {
        unsigned* gcnt = sync + (blockIdx.x >> 5) * 64;
        unsigned* mcnt = sync + 8 * 64;
        unsigned* gen  = sync + 9 * 64;
        bool released = false;
        unsigned p = __hip_atomic_fetch_add(gcnt, 1u, __ATOMIC_RELEASE,
                                            __HIP_MEMORY_SCOPE_AGENT);
        if (p == 31u) {
            __builtin_amdgcn_fence(__ATOMIC_ACQUIRE, "agent");
            __hip_atomic_store(gcnt, 0u, __ATOMIC_RELAXED,
                               __HIP_MEMORY_SCOPE_AGENT);
            unsigned q = __hip_atomic_fetch_add(mcnt, 1u, __ATOMIC_RELEASE,
                                                __HIP_MEMORY_SCOPE_AGENT);
            if (q == 7u) {
                __builtin_amdgcn_fence(__ATOMIC_ACQUIRE, "agent");
                __hip_atomic_store(mcnt, 0u, __ATOMIC_RELAXED,
                                   __HIP_MEMORY_SCOPE_AGENT);
                __hip_atomic_fetch_add(gen, 1u, __ATOMIC_RELEASE,
                                       __HIP_MEMORY_SCOPE_AGENT);
                released = true;
            }
        }
        if (!released) {
            while (__hip_atomic_load(gen, __ATOMIC_RELAXED,
                                     __HIP_MEMORY_SCOPE_AGENT) < target) {
                __builtin_amdgcn_s_sleep(1);
            }
        }
        __builtin_amdgcn_fence(__ATOMIC_ACQUIRE, "agent");
    }
    __syncthreads();
}

// Persistent GRU, BOTH sequences. 256 blocks x 512 threads, 1 block/CU,
// 2 waves/SIMD (VGPR cap 256). Block b: sequence s=b>>7, hidden indices
// [i0,i0+16) -> 48 W_hh rows. 8 waves x 6 rows/wave; lane l owns columns
// {e*256 + 4l .. +4} for e=0..7 -> w[6][32] = 192 arch VGPRs, zero-conflict
// ds_read_b128 on h, perfectly coalesced one-time weight load.
__global__ __launch_bounds__(512, 2) void gru_pair_kernel(
    const float* __restrict__ xp1, const float* __restrict__ xp2,
    const float* __restrict__ Whh1, const float* __restrict__ Whh2,
    const float* __restrict__ bhh1, const float* __restrict__ bhh2,
    float* __restrict__ h1b0, float* __restrict__ h1b1,
    float* __restrict__ h2b0, float* __restrict__ h2b1,
    unsigned* __restrict__ sync) {
    const int tid  = threadIdx.x;
    const int lane = tid & 63;
    const int wv   = tid >> 6;          // 0..7
    const int b    = blockIdx.x;
    const int s    = b >> 7;
    const int i0   = (b & 127) * 16;
    const float* xp  = s ? xp2  : xp1;
    const float* Whh = s ? Whh2 : Whh1;
    const float* bhh = s ? bhh2 : bhh1;
    float* hb0 = s ? h2b0 : h1b0;
    float* hb1 = s ? h2b1 : h1b1;

    __shared__ float h_s[kH];
    __shared__ float hp_s[48];

    // one-time register-resident weight load:
    // lr = wv*6+p in [0,48), gate g=lr>>4, idx j=lr&15, row rg=g*kH+i0+j
    float w[6][32];
    float bias[6];
#pragma unroll
    for (int p = 0; p < 6; ++p) {
        const int lr = wv * 6 + p;
        const int g  = lr >> 4, j = lr & 15;
        const int rg = g * kH + i0 + j;
        bias[p] = bhh[rg];
        const float* wr = Whh + (size_t)rg * kH;
#pragma unroll
        for (int e = 0; e < 8; ++e) {
            float4 v = *(const float4*)(wr + e * 256 + lane * 4);
            w[p][e * 4 + 0] = v.x; w[p][e * 4 + 1] = v.y;
            w[p][e * 4 + 2] = v.z; w[p][e * 4 + 3] = v.w;
        }
    }
    {
        const int k = tid * 4;
        *(float4*)&h_s[k] = make_float4(0.f, 0.f, 0.f, 0.f);
    }
    __syncthreads();

    float xr = 0.f, xz = 0.f, xn = 0.f;
    if (tid < 16) {
        const int i = i0 + tid;
        xr = xp[i]; xz = xp[kH + i]; xn = xp[2 * kH + i];
    }

    for (int t = 0; t < kT; ++t) {
        // matvec: 6 rows/wave, weights in regs, h from LDS (conflict-free)
        float acc[6];
#pragma unroll
        for (int p = 0; p < 6; ++p) acc[p] = 0.f;
#pragma unroll
        for (int e = 0; e < 8; ++e) {
            const float4 hv = *(const float4*)&h_s[e * 256 + lane * 4];
#pragma unroll
            for (int p = 0; p < 6; ++p) {
                acc[p] = fmaf(w[p][e * 4 + 0], hv.x, acc[p]);
                acc[p] = fmaf(w[p][e * 4 + 1], hv.y, acc[p]);
                acc[p] = fmaf(w[p][e * 4 + 2], hv.z, acc[p]);
                acc[p] = fmaf(w[p][e * 4 + 3], hv.w, acc[p]);
            }
        }
#pragma unroll
        for (int p = 0; p < 6; ++p) {
            float a = acc[p];
#pragma unroll
            for (int off = 32; off; off >>= 1) a += __shfl_down(a, off, 64);
            if (lane == 0) hp_s[wv * 6 + p] = a + bias[p];
        }
        __syncthreads();

        // gates + h update (threads 0..15 own the block's 16 indices)
        float* dst = ((t + 1) & 1) ? hb1 : hb0;
        float xr_n = 0.f, xz_n = 0.f, xn_n = 0.f;
        if (tid < 16) {
            const int i = i0 + tid;
            const float r = 1.f / (1.f + expf(-(xr + hp_s[tid])));
            const float z = 1.f / (1.f + expf(-(xz + hp_s[16 + tid])));
            const float n = tanhf(xn + r * hp_s[32 + tid]);
            dst[i] = (1.f - z) * n + z * h_s[i];
            // prefetch xp[t+1] BEFORE arrival: the release's vmcnt(0) wait
            // absorbs this latency while other blocks are still arriving
            if (t + 1 < kT) {
                const float* xpt = xp + (size_t)(t + 1) * kTH;
                xr_n = xpt[i]; xz_n = xpt[kH + i]; xn_n = xpt[2 * kH + i];
            }
        }

        grid_barrier(sync, (unsigned)(t + 1));

        xr = xr_n; xz = xz_n; xn = xn_n;
        // reload full h into LDS: 512 threads x one float4
        {
            const int k = tid * 4;
            float4 hv = *(const float4*)&dst[k];
            *(float4*)&h_s[k] = hv;
        }
        __syncthreads();
    }
}

// fc1(relu) -> fc2 -> log_softmax, single block of 256 threads
__global__ __launch_bounds__(256) void head_kernel(
    const float* __restrict__ h1, const float* __restrict__ h2,
    const float* __restrict__ fc1w, const float* __restrict__ fc1b,
    const float* __restrict__ fc2w, const float* __restrict__ fc2b,
    float* __restrict__ out) {
    __shared__ float cat[2 * kH];
    __shared__ float o1[256];
    __shared__ float logits[3];
    const int tid  = threadIdx.x;
    const int lane = tid & 63;
    const int wave = tid >> 6;

    for (int k = tid; k < kH; k += 256) {
        cat[k]      = h1[k];
        cat[kH + k] = h2[k];
    }
    __syncthreads();

    for (int r = wave; r < 256; r += 4) {
        const float* wr = fc1w + (size_t)r * (2 * kH);
        float acc = 0.f;
        for (int j = lane; j < 2 * kH; j += 64) acc = fmaf(wr[j], cat[j], acc);
#pragma unroll
        for (int off = 32; off; off >>= 1) acc += __shfl_down(acc, off, 64);
        if (lane == 0) o1[r] = fmaxf(acc + fc1b[r], 0.f);
    }
    __syncthreads();

    if (tid < 3) {
        float acc = fc2b[tid];
        const float* wr = fc2w + tid * 256;
        for (int j = 0; j < 256; ++j) acc = fmaf(wr[j], o1[j], acc);
        logits[tid] = acc;
    }
    __syncthreads();

    if (tid == 0) {
        float m = fmaxf(logits[0], fmaxf(logits[1], logits[2]));
        float s = expf(logits[0] - m) + expf(logits[1] - m) + expf(logits[2] - m);
        float ls = logf(s);
        out[0] = logits[0] - m - ls;
        out[1] = logits[1] - m - ls;
        out[2] = logits[2] - m - ls;
    }
}

extern "C" void kernel_launch(void* const* d_in, const int* in_sizes, int n_in,
                              void* d_out, int out_size, void* d_ws,
                              size_t ws_size, hipStream_t stream) {
    const float* x1   = (const float*)d_in[0];
    const float* x2   = (const float*)d_in[1];
    const float* Wih1 = (const float*)d_in[2];
    const float* Whh1 = (const float*)d_in[3];
    const float* bih1 = (const float*)d_in[4];
    const float* bhh1 = (const float*)d_in[5];
    const float* Wih2 = (const float*)d_in[6];
    const float* Whh2 = (const float*)d_in[7];
    const float* bih2 = (const float*)d_in[8];
    const float* bhh2 = (const float*)d_in[9];
    const float* fc1w = (const float*)d_in[10];
    const float* fc1b = (const float*)d_in[11];
    const float* fc2w = (const float*)d_in[12];
    const float* fc2b = (const float*)d_in[13];
    float* out = (float*)d_out;

    char* ws = (char*)d_ws;
    float* xp1 = (float*)ws;
    float* xp2 = xp1 + (size_t)kT * kTH;
    float* hb  = xp2 + (size_t)kT * kTH;
    float* h1b0 = hb;
    float* h1b1 = hb + kH;
    float* h2b0 = hb + 2 * kH;
    float* h2b1 = hb + 3 * kH;
    unsigned* sync = (unsigned*)(hb + 4 * kH);

    init_sync_kernel<<<1, 1024, 0, stream>>>(sync);

    gemm_xp_kernel<<<dim3(kTH / 64, kT / 64, 2), 256, 0, stream>>>(
        x1, x2, Wih1, Wih2, bih1, bih2, xp1, xp2);

    gru_pair_kernel<<<dim3(kNB), dim3(512), 0, stream>>>(
        xp1, xp2, Whh1, Whh2, bhh1, bhh2, h1b0, h1b1, h2b0, h2b1, sync);

    head_kernel<<<1, 256, 0, stream>>>(h1b0, h2b0, fc1w, fc1b, fc2w, fc2b, out);
}

// Round 6
// 21929.083 us; speedup vs baseline: 5.6849x; 1.9781x over previous
//
#include <hip/hip_runtime.h>
#include <hip/hip_bf16.h>

// Problem dims
constexpr int kH  = 2048;          // hidden
constexpr int kD  = 1024;          // input dim
constexpr int kT  = 4096;          // timesteps
constexpr int kTH = 3 * kH;        // 6144 gate rows
constexpr int kNB = 256;           // GRU grid blocks (both sequences)

// ---------------------------------------------------------------------------
// Round-5 post-mortem (40.4 ms GRU, 9.87 us/step, conflicts=0):
// remaining cost = per-step cache maintenance (acquire buffer_inv on every
// CU + release buffer_wbl2 on every arrival) + barrier tree latency.
// Round-6 change: h exchange goes through AGENT-scope RELAXED atomics
// (sc0+sc1 -> bypass L1/L2, coherent at Infinity Cache). h lines then never
// exist in any L1/L2, so NO fences are needed at all. Ordering h-store ->
// arrival via explicit `s_waitcnt vmcnt(0)`. Barrier split into two
// independent 128-block trees (one per sequence) so jitter doesn't couple.
// ---------------------------------------------------------------------------

__global__ void init_sync_kernel(unsigned* __restrict__ sync) {
    sync[threadIdx.x] = 0u;   // 1024 words (2 x 512-word per-seq regions)
}

// fp32 tiled GEMM: xp[t][j] = sum_k x[t][k] * Wih[j][k] + bih[j]
__global__ __launch_bounds__(256) void gemm_xp_kernel(
    const float* __restrict__ x1, const float* __restrict__ x2,
    const float* __restrict__ Wih1, const float* __restrict__ Wih2,
    const float* __restrict__ bih1, const float* __restrict__ bih2,
    float* __restrict__ xp1, float* __restrict__ xp2) {
    const float* x  = blockIdx.z ? x2   : x1;
    const float* W  = blockIdx.z ? Wih2 : Wih1;
    const float* bi = blockIdx.z ? bih2 : bih1;
    float*       xp = blockIdx.z ? xp2  : xp1;

    __shared__ float As[16][68];
    __shared__ float Bs[16][68];

    const int tid  = threadIdx.x;
    const int tx   = tid & 15, ty = tid >> 4;
    const int lrow = tid >> 2;
    const int lk   = (tid & 3) * 4;
    const int m0   = blockIdx.y * 64;
    const int n0   = blockIdx.x * 64;

    float acc[4][4] = {};

    for (int k0 = 0; k0 < kD; k0 += 16) {
        float4 av = *(const float4*)(x + (size_t)(m0 + lrow) * kD + k0 + lk);
        float4 bv = *(const float4*)(W + (size_t)(n0 + lrow) * kD + k0 + lk);
        __syncthreads();
        As[lk + 0][lrow] = av.x; As[lk + 1][lrow] = av.y;
        As[lk + 2][lrow] = av.z; As[lk + 3][lrow] = av.w;
        Bs[lk + 0][lrow] = bv.x; Bs[lk + 1][lrow] = bv.y;
        Bs[lk + 2][lrow] = bv.z; Bs[lk + 3][lrow] = bv.w;
        __syncthreads();
#pragma unroll
        for (int kk = 0; kk < 16; ++kk) {
            float4 a = *(const float4*)&As[kk][ty * 4];
            float4 b = *(const float4*)&Bs[kk][tx * 4];
            float aa[4] = {a.x, a.y, a.z, a.w};
            float bb[4] = {b.x, b.y, b.z, b.w};
#pragma unroll
            for (int i = 0; i < 4; ++i)
#pragma unroll
                for (int j = 0; j < 4; ++j)
                    acc[i][j] = fmaf(aa[i], bb[j], acc[i][j]);
        }
    }

    float4 bb4 = *(const float4*)(bi + n0 + tx * 4);
    float bArr[4] = {bb4.x, bb4.y, bb4.z, bb4.w};
#pragma unroll
    for (int i = 0; i < 4; ++i) {
        float4 o;
        o.x = acc[i][0] + bArr[0];
        o.y = acc[i][1] + bArr[1];
        o.z = acc[i][2] + bArr[2];
        o.w = acc[i][3] + bArr[3];
        *(float4*)(xp + (size_t)(m0 + ty * 4 + i) * kTH + n0 + tx * 4) = o;
    }
}

// Per-sequence two-level grid barrier over 128 blocks. base layout
// (64-word = 256 B strides): base[g*64] g=0..3 group counters (32 each),
// base[256] master (4 groups), base[320] generation. ZERO cache ops:
// relaxed RMWs/loads only; h data is coherent by construction (sc0+sc1).
__device__ __forceinline__ void grid_barrier_seq(unsigned* __restrict__ base,
                                                 unsigned target, int gid) {
    __syncthreads();
    if (threadIdx.x == 0) {
        unsigned* gcnt = base + gid * 64;
        unsigned* mcnt = base + 4 * 64;
        unsigned* gen  = base + 5 * 64;
        // h stores (sc0+sc1, this wave) must be at the coherent point before
        // the arrival RMW lands there. vmcnt(0) orders both; no cache ops.
        asm volatile("s_waitcnt vmcnt(0)" ::: "memory");
        bool released = false;
        unsigned p = __hip_atomic_fetch_add(gcnt, 1u, __ATOMIC_RELAXED,
                                            __HIP_MEMORY_SCOPE_AGENT);
        if (p == 31u) {
            __hip_atomic_store(gcnt, 0u, __ATOMIC_RELAXED,
                               __HIP_MEMORY_SCOPE_AGENT);
            unsigned q = __hip_atomic_fetch_add(mcnt, 1u, __ATOMIC_RELAXED,
                                                __HIP_MEMORY_SCOPE_AGENT);
            if (q == 3u) {
                __hip_atomic_store(mcnt, 0u, __ATOMIC_RELAXED,
                                   __HIP_MEMORY_SCOPE_AGENT);
                __hip_atomic_fetch_add(gen, 1u, __ATOMIC_RELAXED,
                                       __HIP_MEMORY_SCOPE_AGENT);
                released = true;
            }
        }
        if (!released) {
            while (__hip_atomic_load(gen, __ATOMIC_RELAXED,
                                     __HIP_MEMORY_SCOPE_AGENT) < target) {
                __builtin_amdgcn_s_sleep(1);
            }
        }
    }
    __syncthreads();
}

// Persistent GRU, BOTH sequences. 256 blocks x 512 threads, 1 block/CU.
// Block b: sequence s=b>>7, hidden indices [i0,i0+16) -> 48 W_hh rows.
// 8 waves x 6 rows/wave; lane l owns cols {e*256+4l..+4}, w[6][32]=192
// regs/thread. h exchange via agent-scope relaxed atomics (L1/L2 bypass).
__global__ __launch_bounds__(512, 2) void gru_pair_kernel(
    const float* __restrict__ xp1, const float* __restrict__ xp2,
    const float* __restrict__ Whh1, const float* __restrict__ Whh2,
    const float* __restrict__ bhh1, const float* __restrict__ bhh2,
    float* __restrict__ h1b0, float* __restrict__ h1b1,
    float* __restrict__ h2b0, float* __restrict__ h2b1,
    unsigned* __restrict__ sync) {
    const int tid  = threadIdx.x;
    const int lane = tid & 63;
    const int wv   = tid >> 6;          // 0..7
    const int b    = blockIdx.x;
    const int s    = b >> 7;
    const int gid  = (b & 127) >> 5;    // group within sequence, 0..3
    const int i0   = (b & 127) * 16;
    const float* xp  = s ? xp2  : xp1;
    const float* Whh = s ? Whh2 : Whh1;
    const float* bhh = s ? bhh2 : bhh1;
    float* hb0 = s ? h2b0 : h1b0;
    float* hb1 = s ? h2b1 : h1b1;
    unsigned* sbase = sync + s * 512;

    __shared__ float h_s[kH];
    __shared__ float hp_s[48];

    // one-time register-resident weight load:
    // lr = wv*6+p in [0,48), gate g=lr>>4, idx j=lr&15, row rg=g*kH+i0+j
    float w[6][32];
    float bias[6];
#pragma unroll
    for (int p = 0; p < 6; ++p) {
        const int lr = wv * 6 + p;
        const int g  = lr >> 4, j = lr & 15;
        const int rg = g * kH + i0 + j;
        bias[p] = bhh[rg];
        const float* wr = Whh + (size_t)rg * kH;
#pragma unroll
        for (int e = 0; e < 8; ++e) {
            float4 v = *(const float4*)(wr + e * 256 + lane * 4);
            w[p][e * 4 + 0] = v.x; w[p][e * 4 + 1] = v.y;
            w[p][e * 4 + 2] = v.z; w[p][e * 4 + 3] = v.w;
        }
    }
    {
        const int k = tid * 4;
        *(float4*)&h_s[k] = make_float4(0.f, 0.f, 0.f, 0.f);
    }
    __syncthreads();

    float xr = 0.f, xz = 0.f, xn = 0.f;
    if (tid < 16) {
        const int i = i0 + tid;
        xr = xp[i]; xz = xp[kH + i]; xn = xp[2 * kH + i];
    }

    for (int t = 0; t < kT; ++t) {
        // matvec: 6 rows/wave, weights in regs, h from LDS (conflict-free)
        float acc[6];
#pragma unroll
        for (int p = 0; p < 6; ++p) acc[p] = 0.f;
#pragma unroll
        for (int e = 0; e < 8; ++e) {
            const float4 hv = *(const float4*)&h_s[e * 256 + lane * 4];
#pragma unroll
            for (int p = 0; p < 6; ++p) {
                acc[p] = fmaf(w[p][e * 4 + 0], hv.x, acc[p]);
                acc[p] = fmaf(w[p][e * 4 + 1], hv.y, acc[p]);
                acc[p] = fmaf(w[p][e * 4 + 2], hv.z, acc[p]);
                acc[p] = fmaf(w[p][e * 4 + 3], hv.w, acc[p]);
            }
        }
#pragma unroll
        for (int p = 0; p < 6; ++p) {
            float a = acc[p];
#pragma unroll
            for (int off = 32; off; off >>= 1) a += __shfl_down(a, off, 64);
            if (lane == 0) hp_s[wv * 6 + p] = a + bias[p];
        }
        __syncthreads();

        // gates + h update (threads 0..15 own the block's 16 indices)
        float* dst = ((t + 1) & 1) ? hb1 : hb0;
        float xr_n = 0.f, xz_n = 0.f, xn_n = 0.f;
        if (tid < 16) {
            const int i = i0 + tid;
            const float r = 1.f / (1.f + expf(-(xr + hp_s[tid])));
            const float z = 1.f / (1.f + expf(-(xz + hp_s[16 + tid])));
            const float n = tanhf(xn + r * hp_s[32 + tid]);
            const float hn = (1.f - z) * n + z * h_s[i];
            // coherent (L1/L2-bypass) publish of this block's h slice
            __hip_atomic_store(&dst[i], hn, __ATOMIC_RELAXED,
                               __HIP_MEMORY_SCOPE_AGENT);
            // prefetch xp[t+1] before arrival; barrier wait absorbs latency
            if (t + 1 < kT) {
                const float* xpt = xp + (size_t)(t + 1) * kTH;
                xr_n = xpt[i]; xz_n = xpt[kH + i]; xn_n = xpt[2 * kH + i];
            }
        }

        grid_barrier_seq(sbase, (unsigned)(t + 1), gid);

        xr = xr_n; xz = xz_n; xn = xn_n;
        // coherent reload of full h into LDS: 512 threads x 4 floats
        // (2 x 64-bit agent-scope loads; lines never touch L1/L2)
        {
            const int k = tid * 4;
            unsigned long long lo = __hip_atomic_load(
                (const unsigned long long*)&dst[k], __ATOMIC_RELAXED,
                __HIP_MEMORY_SCOPE_AGENT);
            unsigned long long hi = __hip_atomic_load(
                (const unsigned long long*)&dst[k + 2], __ATOMIC_RELAXED,
                __HIP_MEMORY_SCOPE_AGENT);
            float4 hv;
            hv.x = __uint_as_float((unsigned)(lo & 0xffffffffu));
            hv.y = __uint_as_float((unsigned)(lo >> 32));
            hv.z = __uint_as_float((unsigned)(hi & 0xffffffffu));
            hv.w = __uint_as_float((unsigned)(hi >> 32));
            *(float4*)&h_s[k] = hv;
        }
        __syncthreads();
    }
}

// fc1(relu) -> fc2 -> log_softmax, single block of 256 threads
__global__ __launch_bounds__(256) void head_kernel(
    const float* __restrict__ h1, const float* __restrict__ h2,
    const float* __restrict__ fc1w, const float* __restrict__ fc1b,
    const float* __restrict__ fc2w, const float* __restrict__ fc2b,
    float* __restrict__ out) {
    __shared__ float cat[2 * kH];
    __shared__ float o1[256];
    __shared__ float logits[3];
    const int tid  = threadIdx.x;
    const int lane = tid & 63;
    const int wave = tid >> 6;

    for (int k = tid; k < kH; k += 256) {
        cat[k]      = h1[k];
        cat[kH + k] = h2[k];
    }
    __syncthreads();

    for (int r = wave; r < 256; r += 4) {
        const float* wr = fc1w + (size_t)r * (2 * kH);
        float acc = 0.f;
        for (int j = lane; j < 2 * kH; j += 64) acc = fmaf(wr[j], cat[j], acc);
#pragma unroll
        for (int off = 32; off; off >>= 1) acc += __shfl_down(acc, off, 64);
        if (lane == 0) o1[r] = fmaxf(acc + fc1b[r], 0.f);
    }
    __syncthreads();

    if (tid < 3) {
        float acc = fc2b[tid];
        const float* wr = fc2w + tid * 256;
        for (int j = 0; j < 256; ++j) acc = fmaf(wr[j], o1[j], acc);
        logits[tid] = acc;
    }
    __syncthreads();

    if (tid == 0) {
        float m = fmaxf(logits[0], fmaxf(logits[1], logits[2]));
        float s = expf(logits[0] - m) + expf(logits[1] - m) + expf(logits[2] - m);
        float ls = logf(s);
        out[0] = logits[0] - m - ls;
        out[1] = logits[1] - m - ls;
        out[2] = logits[2] - m - ls;
    }
}

extern "C" void kernel_launch(void* const* d_in, const int* in_sizes, int n_in,
                              void* d_out, int out_size, void* d_ws,
                              size_t ws_size, hipStream_t stream) {
    const float* x1   = (const float*)d_in[0];
    const float* x2   = (const float*)d_in[1];
    const float* Wih1 = (const float*)d_in[2];
    const float* Whh1 = (const float*)d_in[3];
    const float* bih1 = (const float*)d_in[4];
    const float* bhh1 = (const float*)d_in[5];
    const float* Wih2 = (const float*)d_in[6];
    const float* Whh2 = (const float*)d_in[7];
    const float* bih2 = (const float*)d_in[8];
    const float* bhh2 = (const float*)d_in[9];
    const float* fc1w = (const float*)d_in[10];
    const float* fc1b = (const float*)d_in[11];
    const float* fc2w = (const float*)d_in[12];
    const float* fc2b = (const float*)d_in[13];
    float* out = (float*)d_out;

    char* ws = (char*)d_ws;
    float* xp1 = (float*)ws;
    float* xp2 = xp1 + (size_t)kT * kTH;
    float* hb  = xp2 + (size_t)kT * kTH;
    float* h1b0 = hb;
    float* h1b1 = hb + kH;
    float* h2b0 = hb + 2 * kH;
    float* h2b1 = hb + 3 * kH;
    unsigned* sync = (unsigned*)(hb + 4 * kH);

    init_sync_kernel<<<1, 1024, 0, stream>>>(sync);

    gemm_xp_kernel<<<dim3(kTH / 64, kT / 64, 2), 256, 0, stream>>>(
        x1, x2, Wih1, Wih2, bih1, bih2, xp1, xp2);

    gru_pair_kernel<<<dim3(kNB), dim3(512), 0, stream>>>(
        xp1, xp2, Whh1, Whh2, bhh1, bhh2, h1b0, h1b1, h2b0, h2b1, sync);

    head_kernel<<<1, 256, 0, stream>>>(h1b0, h2b0, fc1w, fc1b, fc2w, fc2b, out);
}

// Round 7
// 20400.130 us; speedup vs baseline: 6.1109x; 1.0749x over previous
//
#include <hip/hip_runtime.h>
#include <hip/hip_bf16.h>

// Problem dims
constexpr int kH  = 2048;          // hidden
constexpr int kD  = 1024;          // input dim
constexpr int kT  = 4096;          // timesteps
constexpr int kTH = 3 * kH;        // 6144 gate rows
constexpr int kNB = 256;           // GRU grid blocks (both sequences)

// ---------------------------------------------------------------------------
// Round-6 post-mortem (18.95 ms GRU, 4.63 us/step): remaining cost =
//  (a) xp prefetch loads issued by wave 0 BEFORE the barrier vmcnt(0) ->
//      arrival waited on L2-miss xp reads;
//  (b) 32 serialized same-line fetch_adds per group + master hop + gen hop
//      + poll hop = ~4 IF round trips;
//  (c) 128arch/128AGPR split -> accvgpr moves double matvec VALU (deferred).
// Round-7: tree barrier -> per-block flag lines (zero serialization) with
// direct 128-flag polling per block (no broadcast hop). xp prefetch moved to
// the polling wave, staged via double-buffered LDS. Wave 0's vmcnt(0) now
// covers ONLY its 16 h stores.
// Flags: sync + seq*2048 words; flag[b] at 16-dword (64 B) stride.
// ---------------------------------------------------------------------------

__global__ void init_sync_kernel(unsigned* __restrict__ sync) {
    sync[blockIdx.x * 1024 + threadIdx.x] = 0u;   // 4096 words
}

// fp32 tiled GEMM: xp[t][j] = sum_k x[t][k] * Wih[j][k] + bih[j]
__global__ __launch_bounds__(256) void gemm_xp_kernel(
    const float* __restrict__ x1, const float* __restrict__ x2,
    const float* __restrict__ Wih1, const float* __restrict__ Wih2,
    const float* __restrict__ bih1, const float* __restrict__ bih2,
    float* __restrict__ xp1, float* __restrict__ xp2) {
    const float* x  = blockIdx.z ? x2   : x1;
    const float* W  = blockIdx.z ? Wih2 : Wih1;
    const float* bi = blockIdx.z ? bih2 : bih1;
    float*       xp = blockIdx.z ? xp2  : xp1;

    __shared__ float As[16][68];
    __shared__ float Bs[16][68];

    const int tid  = threadIdx.x;
    const int tx   = tid & 15, ty = tid >> 4;
    const int lrow = tid >> 2;
    const int lk   = (tid & 3) * 4;
    const int m0   = blockIdx.y * 64;
    const int n0   = blockIdx.x * 64;

    float acc[4][4] = {};

    for (int k0 = 0; k0 < kD; k0 += 16) {
        float4 av = *(const float4*)(x + (size_t)(m0 + lrow) * kD + k0 + lk);
        float4 bv = *(const float4*)(W + (size_t)(n0 + lrow) * kD + k0 + lk);
        __syncthreads();
        As[lk + 0][lrow] = av.x; As[lk + 1][lrow] = av.y;
        As[lk + 2][lrow] = av.z; As[lk + 3][lrow] = av.w;
        Bs[lk + 0][lrow] = bv.x; Bs[lk + 1][lrow] = bv.y;
        Bs[lk + 2][lrow] = bv.z; Bs[lk + 3][lrow] = bv.w;
        __syncthreads();
#pragma unroll
        for (int kk = 0; kk < 16; ++kk) {
            float4 a = *(const float4*)&As[kk][ty * 4];
            float4 b = *(const float4*)&Bs[kk][tx * 4];
            float aa[4] = {a.x, a.y, a.z, a.w};
            float bb[4] = {b.x, b.y, b.z, b.w};
#pragma unroll
            for (int i = 0; i < 4; ++i)
#pragma unroll
                for (int j = 0; j < 4; ++j)
                    acc[i][j] = fmaf(aa[i], bb[j], acc[i][j]);
        }
    }

    float4 bb4 = *(const float4*)(bi + n0 + tx * 4);
    float bArr[4] = {bb4.x, bb4.y, bb4.z, bb4.w};
#pragma unroll
    for (int i = 0; i < 4; ++i) {
        float4 o;
        o.x = acc[i][0] + bArr[0];
        o.y = acc[i][1] + bArr[1];
        o.z = acc[i][2] + bArr[2];
        o.w = acc[i][3] + bArr[3];
        *(float4*)(xp + (size_t)(m0 + ty * 4 + i) * kTH + n0 + tx * 4) = o;
    }
}

// Persistent GRU, BOTH sequences. 256 blocks x 512 threads, 1 block/CU.
// Block b: sequence s=b>>7, hidden indices [i0,i0+16) -> 48 W_hh rows.
// 8 waves x 6 rows/wave; lane l owns cols {e*256+4l..+4}, w[6][32]=192
// regs/thread. h exchange via agent-scope relaxed atomics (L1/L2 bypass).
// Barrier: flag[b]=t+1 after vmcnt(0) on h stores; wave 1 polls all 128
// flags of its sequence; wave 1 also prefetches xp[t+1] into LDS.
__global__ __launch_bounds__(512, 2) void gru_pair_kernel(
    const float* __restrict__ xp1, const float* __restrict__ xp2,
    const float* __restrict__ Whh1, const float* __restrict__ Whh2,
    const float* __restrict__ bhh1, const float* __restrict__ bhh2,
    float* __restrict__ h1b0, float* __restrict__ h1b1,
    float* __restrict__ h2b0, float* __restrict__ h2b1,
    unsigned* __restrict__ sync) {
    const int tid  = threadIdx.x;
    const int lane = tid & 63;
    const int wv   = tid >> 6;          // 0..7
    const int b    = blockIdx.x;
    const int s    = b >> 7;
    const int lb   = b & 127;           // block index within sequence
    const int i0   = lb * 16;
    const float* xp  = s ? xp2  : xp1;
    const float* Whh = s ? Whh2 : Whh1;
    const float* bhh = s ? bhh2 : bhh1;
    float* hb0 = s ? h2b0 : h1b0;
    float* hb1 = s ? h2b1 : h1b1;
    unsigned* flags = sync + s * 2048;      // flag[j] at flags[j*16]

    __shared__ float h_s[kH];
    __shared__ float hp_s[48];
    __shared__ float xp_s[2][48];

    // one-time register-resident weight load:
    // lr = wv*6+p in [0,48), gate g=lr>>4, idx j=lr&15, row rg=g*kH+i0+j
    float w[6][32];
    float bias[6];
#pragma unroll
    for (int p = 0; p < 6; ++p) {
        const int lr = wv * 6 + p;
        const int g  = lr >> 4, j = lr & 15;
        const int rg = g * kH + i0 + j;
        bias[p] = bhh[rg];
        const float* wr = Whh + (size_t)rg * kH;
#pragma unroll
        for (int e = 0; e < 8; ++e) {
            float4 v = *(const float4*)(wr + e * 256 + lane * 4);
            w[p][e * 4 + 0] = v.x; w[p][e * 4 + 1] = v.y;
            w[p][e * 4 + 2] = v.z; w[p][e * 4 + 3] = v.w;
        }
    }
    {
        const int k = tid * 4;
        *(float4*)&h_s[k] = make_float4(0.f, 0.f, 0.f, 0.f);
    }
    // preload xp[0] into xp_s[0]
    if (tid < 48) {
        xp_s[0][tid] = xp[(size_t)(tid >> 4) * kH + i0 + (tid & 15)];
    }
    __syncthreads();

    for (int t = 0; t < kT; ++t) {
        // matvec: 6 rows/wave, weights in regs, h from LDS (conflict-free)
        float acc[6];
#pragma unroll
        for (int p = 0; p < 6; ++p) acc[p] = 0.f;
#pragma unroll
        for (int e = 0; e < 8; ++e) {
            const float4 hv = *(const float4*)&h_s[e * 256 + lane * 4];
#pragma unroll
            for (int p = 0; p < 6; ++p) {
                acc[p] = fmaf(w[p][e * 4 + 0], hv.x, acc[p]);
                acc[p] = fmaf(w[p][e * 4 + 1], hv.y, acc[p]);
                acc[p] = fmaf(w[p][e * 4 + 2], hv.z, acc[p]);
                acc[p] = fmaf(w[p][e * 4 + 3], hv.w, acc[p]);
            }
        }
#pragma unroll
        for (int p = 0; p < 6; ++p) {
            float a = acc[p];
#pragma unroll
            for (int off = 32; off; off >>= 1) a += __shfl_down(a, off, 64);
            if (lane == 0) hp_s[wv * 6 + p] = a + bias[p];
        }
        __syncthreads();   // (A) hp_s ready; h_s reads done

        float* dst = ((t + 1) & 1) ? hb1 : hb0;
        if (wv == 0) {
            // gates + coherent publish; vmcnt(0) covers ONLY these stores
            if (lane < 16) {
                const int i = i0 + lane;
                const float xr = xp_s[t & 1][lane];
                const float xz = xp_s[t & 1][16 + lane];
                const float xn = xp_s[t & 1][32 + lane];
                const float r = 1.f / (1.f + expf(-(xr + hp_s[lane])));
                const float z = 1.f / (1.f + expf(-(xz + hp_s[16 + lane])));
                const float n = tanhf(xn + r * hp_s[32 + lane]);
                const float hn = (1.f - z) * n + z * h_s[i];
                __hip_atomic_store(&dst[i], hn, __ATOMIC_RELAXED,
                                   __HIP_MEMORY_SCOPE_AGENT);
            }
            asm volatile("s_waitcnt vmcnt(0)" ::: "memory");
            if (lane == 0) {
                __hip_atomic_store(&flags[lb * 16], (unsigned)(t + 1),
                                   __ATOMIC_RELAXED, __HIP_MEMORY_SCOPE_AGENT);
            }
        } else if (wv == 1) {
            // stage xp[t+1] for wave 0 (keeps wave 0's vmcnt clean)
            if (t + 1 < kT && lane < 48) {
                xp_s[(t + 1) & 1][lane] =
                    xp[(size_t)(t + 1) * kTH + (size_t)(lane >> 4) * kH + i0 +
                       (lane & 15)];
            }
            // poll all 128 flags of this sequence (2 per lane)
            const unsigned tgt = (unsigned)(t + 1);
            const unsigned* fa = flags + lane * 16;
            const unsigned* fb = flags + (lane + 64) * 16;
            for (;;) {
                unsigned f1 = __hip_atomic_load(fa, __ATOMIC_RELAXED,
                                                __HIP_MEMORY_SCOPE_AGENT);
                unsigned f2 = __hip_atomic_load(fb, __ATOMIC_RELAXED,
                                                __HIP_MEMORY_SCOPE_AGENT);
                if (__all((f1 >= tgt) && (f2 >= tgt))) break;
                __builtin_amdgcn_s_sleep(1);
            }
        }
        __syncthreads();   // (B) released once wave 1 saw all flags

        // coherent reload of full h into LDS: 512 threads x 4 floats
        {
            const int k = tid * 4;
            unsigned long long lo = __hip_atomic_load(
                (const unsigned long long*)&dst[k], __ATOMIC_RELAXED,
                __HIP_MEMORY_SCOPE_AGENT);
            unsigned long long hi = __hip_atomic_load(
                (const unsigned long long*)&dst[k + 2], __ATOMIC_RELAXED,
                __HIP_MEMORY_SCOPE_AGENT);
            float4 hv;
            hv.x = __uint_as_float((unsigned)(lo & 0xffffffffu));
            hv.y = __uint_as_float((unsigned)(lo >> 32));
            hv.z = __uint_as_float((unsigned)(hi & 0xffffffffu));
            hv.w = __uint_as_float((unsigned)(hi >> 32));
            *(float4*)&h_s[k] = hv;
        }
        __syncthreads();   // (C) h_s ready for next matvec
    }
}

// fc1(relu) -> fc2 -> log_softmax, single block of 256 threads
__global__ __launch_bounds__(256) void head_kernel(
    const float* __restrict__ h1, const float* __restrict__ h2,
    const float* __restrict__ fc1w, const float* __restrict__ fc1b,
    const float* __restrict__ fc2w, const float* __restrict__ fc2b,
    float* __restrict__ out) {
    __shared__ float cat[2 * kH];
    __shared__ float o1[256];
    __shared__ float logits[3];
    const int tid  = threadIdx.x;
    const int lane = tid & 63;
    const int wave = tid >> 6;

    for (int k = tid; k < kH; k += 256) {
        cat[k]      = h1[k];
        cat[kH + k] = h2[k];
    }
    __syncthreads();

    for (int r = wave; r < 256; r += 4) {
        const float* wr = fc1w + (size_t)r * (2 * kH);
        float acc = 0.f;
        for (int j = lane; j < 2 * kH; j += 64) acc = fmaf(wr[j], cat[j], acc);
#pragma unroll
        for (int off = 32; off; off >>= 1) acc += __shfl_down(acc, off, 64);
        if (lane == 0) o1[r] = fmaxf(acc + fc1b[r], 0.f);
    }
    __syncthreads();

    if (tid < 3) {
        float acc = fc2b[tid];
        const float* wr = fc2w + tid * 256;
        for (int j = 0; j < 256; ++j) acc = fmaf(wr[j], o1[j], acc);
        logits[tid] = acc;
    }
    __syncthreads();

    if (tid == 0) {
        float m = fmaxf(logits[0], fmaxf(logits[1], logits[2]));
        float s = expf(logits[0] - m) + expf(logits[1] - m) + expf(logits[2] - m);
        float ls = logf(s);
        out[0] = logits[0] - m - ls;
        out[1] = logits[1] - m - ls;
        out[2] = logits[2] - m - ls;
    }
}

extern "C" void kernel_launch(void* const* d_in, const int* in_sizes, int n_in,
                              void* d_out, int out_size, void* d_ws,
                              size_t ws_size, hipStream_t stream) {
    const float* x1   = (const float*)d_in[0];
    const float* x2   = (const float*)d_in[1];
    const float* Wih1 = (const float*)d_in[2];
    const float* Whh1 = (const float*)d_in[3];
    const float* bih1 = (const float*)d_in[4];
    const float* bhh1 = (const float*)d_in[5];
    const float* Wih2 = (const float*)d_in[6];
    const float* Whh2 = (const float*)d_in[7];
    const float* bih2 = (const float*)d_in[8];
    const float* bhh2 = (const float*)d_in[9];
    const float* fc1w = (const float*)d_in[10];
    const float* fc1b = (const float*)d_in[11];
    const float* fc2w = (const float*)d_in[12];
    const float* fc2b = (const float*)d_in[13];
    float* out = (float*)d_out;

    char* ws = (char*)d_ws;
    float* xp1 = (float*)ws;
    float* xp2 = xp1 + (size_t)kT * kTH;
    float* hb  = xp2 + (size_t)kT * kTH;
    float* h1b0 = hb;
    float* h1b1 = hb + kH;
    float* h2b0 = hb + 2 * kH;
    float* h2b1 = hb + 3 * kH;
    unsigned* sync = (unsigned*)(hb + 4 * kH);

    init_sync_kernel<<<4, 1024, 0, stream>>>(sync);

    gemm_xp_kernel<<<dim3(kTH / 64, kT / 64, 2), 256, 0, stream>>>(
        x1, x2, Wih1, Wih2, bih1, bih2, xp1, xp2);

    gru_pair_kernel<<<dim3(kNB), dim3(512), 0, stream>>>(
        xp1, xp2, Whh1, Whh2, bhh1, bhh2, h1b0, h1b1, h2b0, h2b1, sync);

    head_kernel<<<1, 256, 0, stream>>>(h1b0, h2b0, fc1w, fc1b, fc2w, fc2b, out);
}